// Round 3
// baseline (132.313 us; speedup 1.0000x reference)
//
#include <hip/hip_runtime.h>
#include <hip/hip_bf16.h>

#define BQ   2
#define NH   12
#define SEQ  2048
#define DIM  64
#define EXQ  64   // end_x (both grids equal -> resample is identity)

#define TENSOR_ELEMS ((size_t)BQ * NH * SEQ * DIM)   // 3,145,728 bf16 each
#define TAB_ROW      128                              // padded dx stride
#define TAB_DYS      63                               // dy in [-31,31]
#define TAB_PER_H    (TAB_DYS * TAB_ROW)              // 8064
#define TAB_ELEMS    (NH * TAB_PER_H)                 // 96768 floats
#define ROPE_BLOCKS  6144                             // 2*BQ*NH*SEQ*16 / 256
#define TAB_BLOCKS   378                              // 96768 / 256

typedef __attribute__((ext_vector_type(8))) short short8;
typedef __attribute__((ext_vector_type(4))) float f32x4;

static __device__ __forceinline__ unsigned int pk2bf(float lo, float hi) {
    union { float f; unsigned int u; } a, b; a.f = lo; b.f = hi;
    unsigned int rl = (a.u + 0x7fffu + ((a.u >> 16) & 1u)) >> 16;  // RNE
    unsigned int rh = (b.u + 0x7fffu + ((b.u >> 16) & 1u)) >> 16;
    return (rh << 16) | (rl & 0xffffu);
}

// ---- Phase 1: RoPE-rotate q,b -> bf16 ws; build per-head decay table -------
// ws layout: xq bf16[TENSOR_ELEMS] | xb bf16[TENSOR_ELEMS] | tab f32[TAB_ELEMS]
__global__ __launch_bounds__(256)
void phase1_kernel(const float* __restrict__ qin,
                   const float* __restrict__ bin,
                   const float* __restrict__ freqs,   // [2, NH, 16]
                   const float* __restrict__ weight,  // [NH]
                   unsigned int* __restrict__ ws_u32,
                   float* __restrict__ tab,
                   int build_tab)
{
    if (blockIdx.x < ROPE_BLOCKS) {
        int t  = blockIdx.x * 256 + threadIdx.x;
        int p4 = t & 15;                 // quad of elements (2 pairs)
        int n  = (t >> 4) & (SEQ - 1);
        int rest = t >> 15;              // (tensor*BQ+b)*NH + h
        int h    = rest % NH;
        int tb   = rest / NH;
        int tensor = tb >> 1;
        int b      = tb & 1;

        float tx = (float)(n & (EXQ - 1));
        float ty = (float)(n >> 6);

        int pr0 = 2 * p4;                // pair indices pr0, pr0+1
        float f0, f1;
        if (p4 < 8) {
            f0 = freqs[h * 16 + pr0];
            f1 = freqs[h * 16 + pr0 + 1];
            f0 *= tx; f1 *= tx;
        } else {
            f0 = freqs[NH * 16 + h * 16 + (pr0 - 16)];
            f1 = freqs[NH * 16 + h * 16 + (pr0 - 15)];
            f0 *= ty; f1 *= ty;
        }

        const float* src = tensor ? bin : qin;
        size_t off = ((size_t)(b * NH + h) * SEQ + n) * DIM + 4 * p4;
        float4 v = *reinterpret_cast<const float4*>(src + off);

        float s0 = sinf(f0), c0 = cosf(f0);
        float s1 = sinf(f1), c1 = cosf(f1);

        float o0 = v.x * c0 - v.y * s0;
        float o1 = v.x * s0 + v.y * c0;
        float o2 = v.z * c1 - v.w * s1;
        float o3 = v.z * s1 + v.w * c1;

        uint2 packed;
        packed.x = pk2bf(o0, o1);
        packed.y = pk2bf(o2, o3);
        size_t uidx = (size_t)tensor * (TENSOR_ELEMS / 2) + (off >> 1);
        *reinterpret_cast<uint2*>(ws_u32 + uidx) = packed;
    } else if (build_tab) {
        int e = (blockIdx.x - ROPE_BLOCKS) * 256 + threadIdx.x;
        if (e < TAB_ELEMS) {
            int h   = e / TAB_PER_H;
            int rem = e % TAB_PER_H;
            int dyi = rem >> 7;
            int dxi = rem & (TAB_ROW - 1);
            float dx = (float)(dxi - 63);
            float dy = (float)(dyi - 31);
            float dist = sqrtf(dx * dx + dy * dy);
            float w  = weight[h];
            float lw = w > 0.f ? w : 0.01f * w;
            tab[e] = exp2f(-1.44269504088896f * lw * dist);
        }
    }
}

// ---- Phase 2: 128x128 MFMA GEMM + fused decay ------------------------------
// MFMA operands SWAPPED: acc[i][j] = mfma(bfr[j], afr[i], acc) computes the
// transposed fragment, so lane l holds out[row0+i*16+(l&15)]
// [col0+j*16+(l>>4)*4 + reg 0..3] -> 4 consecutive cols = one f32x4 store.
template<bool USE_TAB>
__global__ __launch_bounds__(256, 3)
void gemm_delta_kernel(const unsigned short* __restrict__ ws,
                       const float* __restrict__ tab,
                       const float* __restrict__ weight,
                       float* __restrict__ out)
{
    const int bh   = blockIdx.z;
    const int h    = bh % NH;
    const int lane = threadIdx.x & 63;
    const int wave = threadIdx.x >> 6;
    const int wr   = wave >> 1, wc = wave & 1;
    const int row0 = blockIdx.y * 128 + wr * 64;
    const int col0 = blockIdx.x * 128 + wc * 64;

    const unsigned short* xq = ws;
    const unsigned short* xb = ws + TENSOR_ELEMS;

    const int r16 = lane & 15;
    const int kg  = lane >> 4;

    const size_t base = (size_t)bh * SEQ * DIM;

    f32x4 acc[4][4];
#pragma unroll
    for (int i = 0; i < 4; ++i)
#pragma unroll
        for (int j = 0; j < 4; ++j)
            acc[i][j] = (f32x4){0.f, 0.f, 0.f, 0.f};

#pragma unroll
    for (int kk = 0; kk < 2; ++kk) {
        short8 afr[4], bfr[4];
        int k = kk * 32 + kg * 8;
#pragma unroll
        for (int i = 0; i < 4; ++i) {
            int arw = row0 + i * 16 + r16;
            int bcl = col0 + i * 16 + r16;
            afr[i] = *reinterpret_cast<const short8*>(xq + base + (size_t)arw * DIM + k);
            bfr[i] = *reinterpret_cast<const short8*>(xb + base + (size_t)bcl * DIM + k);
        }
#pragma unroll
        for (int i = 0; i < 4; ++i)
#pragma unroll
            for (int j = 0; j < 4; ++j)
                acc[i][j] = __builtin_amdgcn_mfma_f32_16x16x32_bf16(
                    bfr[j], afr[i], acc[i][j], 0, 0, 0);
    }

    if (USE_TAB) {
        // dy is wave-uniform: qy = row0>>6, ky = col0>>6
        const int dyi = (col0 >> 6) - (row0 >> 6) + 31;
        const float* tabrow = tab + h * TAB_PER_H + dyi * TAB_ROW + 63;
#pragma unroll
        for (int i = 0; i < 4; ++i) {
            int qx = i * 16 + r16;                 // row & 63
            int row = row0 + qx;
            float* op = out + ((size_t)bh * SEQ + row) * SEQ + col0 + kg * 4;
            const float* rp = tabrow - qx + kg * 4;
#pragma unroll
            for (int j = 0; j < 4; ++j) {
                f32x4 t;
                t[0] = rp[j * 16 + 0];
                t[1] = rp[j * 16 + 1];
                t[2] = rp[j * 16 + 2];
                t[3] = rp[j * 16 + 3];
                f32x4 v = acc[i][j] * t;
                __builtin_nontemporal_store(v, reinterpret_cast<f32x4*>(op + j * 16));
            }
        }
    } else {
        float w  = weight[h];
        float lw = w > 0.f ? w : 0.01f * w;
        float scale = -lw * 1.44269504088896f;
#pragma unroll
        for (int i = 0; i < 4; ++i) {
            int qx = i * 16 + r16;
            int row = row0 + qx;
            float qy = (float)(row >> 6);
            float* op = out + ((size_t)bh * SEQ + row) * SEQ + col0 + kg * 4;
#pragma unroll
            for (int j = 0; j < 4; ++j) {
                f32x4 v;
#pragma unroll
                for (int r = 0; r < 4; ++r) {
                    int col = col0 + j * 16 + kg * 4 + r;
                    float kx = (float)(col & (EXQ - 1));
                    float ky = (float)(col >> 6);
                    float dx = kx - (float)qx, dy = ky - qy;
                    float dist = sqrtf(dx * dx + dy * dy);
                    v[r] = acc[i][j][r] * exp2f(scale * dist);
                }
                __builtin_nontemporal_store(v, reinterpret_cast<f32x4*>(op + j * 16));
            }
        }
    }
}

extern "C" void kernel_launch(void* const* d_in, const int* in_sizes, int n_in,
                              void* d_out, int out_size, void* d_ws, size_t ws_size,
                              hipStream_t stream) {
    const float* q  = (const float*)d_in[0];
    const float* b  = (const float*)d_in[1];
    const float* fr = (const float*)d_in[2];
    const float* wt = (const float*)d_in[3];
    float* out = (float*)d_out;

    const size_t need_tensors = 2 * TENSOR_ELEMS * sizeof(unsigned short);
    const size_t need_full    = need_tensors + TAB_ELEMS * sizeof(float);
    if (ws_size < need_tensors) return;
    const bool use_tab = ws_size >= need_full;

    unsigned short* ws16 = (unsigned short*)d_ws;
    float* tab = (float*)(ws16 + 2 * TENSOR_ELEMS);

    int grid1 = ROPE_BLOCKS + (use_tab ? TAB_BLOCKS : 0);
    phase1_kernel<<<grid1, 256, 0, stream>>>(q, b, fr, wt,
                                             (unsigned int*)d_ws, tab,
                                             use_tab ? 1 : 0);

    dim3 grid(SEQ / 128, SEQ / 128, BQ * NH);
    if (use_tab)
        gemm_delta_kernel<true><<<grid, 256, 0, stream>>>(ws16, tab, wt, out);
    else
        gemm_delta_kernel<false><<<grid, 256, 0, stream>>>(ws16, tab, wt, out);
}

// Round 4
// 102.771 us; speedup vs baseline: 1.2875x; 1.2875x over previous
//
#include <hip/hip_runtime.h>
#include <hip/hip_bf16.h>

#define BQ   2
#define NH   12
#define SEQ  2048
#define DIM  64
#define EXQ  64   // end_x (both grids equal -> resample is identity)

#define TENSOR_ELEMS ((size_t)BQ * NH * SEQ * DIM)   // 3,145,728 bf16 each
#define TAB_ROW      128                              // padded dx stride
#define TAB_DYS      63                               // dy in [-31,31]
#define TAB_PER_H    (TAB_DYS * TAB_ROW)              // 8064
#define TAB_ELEMS    (NH * TAB_PER_H)                 // 96768 floats
#define ROPE_BLOCKS  6144                             // 2*BQ*NH*SEQ*16 / 256
#define TAB_BLOCKS   378                              // 96768 / 256

typedef __attribute__((ext_vector_type(8))) short short8;
typedef __attribute__((ext_vector_type(4))) float f32x4;

static __device__ __forceinline__ unsigned int pk2bf(float lo, float hi) {
    union { float f; unsigned int u; } a, b; a.f = lo; b.f = hi;
    unsigned int rl = (a.u + 0x7fffu + ((a.u >> 16) & 1u)) >> 16;  // RNE
    unsigned int rh = (b.u + 0x7fffu + ((b.u >> 16) & 1u)) >> 16;
    return (rh << 16) | (rl & 0xffffu);
}

// ---- Phase 1: RoPE-rotate q,b -> bf16 ws; build per-head decay table -------
// ws layout: xq bf16[TENSOR_ELEMS] | xb bf16[TENSOR_ELEMS] | tab f32[TAB_ELEMS]
__global__ __launch_bounds__(256)
void phase1_kernel(const float* __restrict__ qin,
                   const float* __restrict__ bin,
                   const float* __restrict__ freqs,   // [2, NH, 16]
                   const float* __restrict__ weight,  // [NH]
                   unsigned int* __restrict__ ws_u32,
                   float* __restrict__ tab,
                   int build_tab)
{
    if (blockIdx.x < ROPE_BLOCKS) {
        int t  = blockIdx.x * 256 + threadIdx.x;
        int p4 = t & 15;                 // quad of elements (2 pairs)
        int n  = (t >> 4) & (SEQ - 1);
        int rest = t >> 15;              // (tensor*BQ+b)*NH + h
        int h    = rest % NH;
        int tb   = rest / NH;
        int tensor = tb >> 1;
        int b      = tb & 1;

        float tx = (float)(n & (EXQ - 1));
        float ty = (float)(n >> 6);

        int pr0 = 2 * p4;                // pair indices pr0, pr0+1
        float f0, f1;
        if (p4 < 8) {
            f0 = freqs[h * 16 + pr0];
            f1 = freqs[h * 16 + pr0 + 1];
            f0 *= tx; f1 *= tx;
        } else {
            f0 = freqs[NH * 16 + h * 16 + (pr0 - 16)];
            f1 = freqs[NH * 16 + h * 16 + (pr0 - 15)];
            f0 *= ty; f1 *= ty;
        }

        const float* src = tensor ? bin : qin;
        size_t off = ((size_t)(b * NH + h) * SEQ + n) * DIM + 4 * p4;
        float4 v = *reinterpret_cast<const float4*>(src + off);

        float s0 = sinf(f0), c0 = cosf(f0);
        float s1 = sinf(f1), c1 = cosf(f1);

        float o0 = v.x * c0 - v.y * s0;
        float o1 = v.x * s0 + v.y * c0;
        float o2 = v.z * c1 - v.w * s1;
        float o3 = v.z * s1 + v.w * c1;

        uint2 packed;
        packed.x = pk2bf(o0, o1);
        packed.y = pk2bf(o2, o3);
        size_t uidx = (size_t)tensor * (TENSOR_ELEMS / 2) + (off >> 1);
        *reinterpret_cast<uint2*>(ws_u32 + uidx) = packed;
    } else if (build_tab) {
        int e = (blockIdx.x - ROPE_BLOCKS) * 256 + threadIdx.x;
        if (e < TAB_ELEMS) {
            int h   = e / TAB_PER_H;
            int rem = e % TAB_PER_H;
            int dyi = rem >> 7;
            int dxi = rem & (TAB_ROW - 1);
            float dx = (float)(dxi - 63);
            float dy = (float)(dyi - 31);
            float dist = sqrtf(dx * dx + dy * dy);
            float w  = weight[h];
            float lw = w > 0.f ? w : 0.01f * w;
            tab[e] = exp2f(-1.44269504088896f * lw * dist);
        }
    }
}

// ---- Phase 2: 128x128 MFMA GEMM + fused decay + LDS-staged coalesced drain -
// Swapped MFMA: acc[i][j] = mfma(bfr[j], afr[i], acc): lane l holds
// row = i*16+(l&15), cols = j*16+(l>>4)*4+{0..3} (block-local within wave tile).
// Epilogue stages 64 block-rows at a time in LDS (32 KB, XOR-swizzled), then
// drains with lane-contiguous f32x4 stores: 2 rows x 512 B = 1 KB full lines
// per wave-instruction.
template<bool USE_TAB>
__global__ __launch_bounds__(256, 3)
void gemm_delta_kernel(const unsigned short* __restrict__ ws,
                       const float* __restrict__ tab,
                       const float* __restrict__ weight,
                       float* __restrict__ out)
{
    __shared__ float lds[64 * 128];       // 32 KB half-tile

    const int bh   = blockIdx.z;
    const int h    = bh % NH;
    const int lane = threadIdx.x & 63;
    const int wave = threadIdx.x >> 6;
    const int wr   = wave >> 1, wc = wave & 1;
    const int brow0 = blockIdx.y * 128;   // block tile origin
    const int bcol0 = blockIdx.x * 128;
    const int row0 = brow0 + wr * 64;     // wave tile origin
    const int col0 = bcol0 + wc * 64;

    const unsigned short* xq = ws;
    const unsigned short* xb = ws + TENSOR_ELEMS;

    const int r16 = lane & 15;
    const int kg  = lane >> 4;

    const size_t base = (size_t)bh * SEQ * DIM;

    f32x4 acc[4][4];
#pragma unroll
    for (int i = 0; i < 4; ++i)
#pragma unroll
        for (int j = 0; j < 4; ++j)
            acc[i][j] = (f32x4){0.f, 0.f, 0.f, 0.f};

#pragma unroll
    for (int kk = 0; kk < 2; ++kk) {
        short8 afr[4], bfr[4];
        int k = kk * 32 + kg * 8;
#pragma unroll
        for (int i = 0; i < 4; ++i) {
            int arw = row0 + i * 16 + r16;
            int bcl = col0 + i * 16 + r16;
            afr[i] = *reinterpret_cast<const short8*>(xq + base + (size_t)arw * DIM + k);
            bfr[i] = *reinterpret_cast<const short8*>(xb + base + (size_t)bcl * DIM + k);
        }
#pragma unroll
        for (int i = 0; i < 4; ++i)
#pragma unroll
            for (int j = 0; j < 4; ++j)
                acc[i][j] = __builtin_amdgcn_mfma_f32_16x16x32_bf16(
                    bfr[j], afr[i], acc[i][j], 0, 0, 0);
    }

    // decay params
    const int dyi = (col0 >> 6) - (row0 >> 6) + 31;            // wave-uniform
    const float* tabrow = USE_TAB ? (tab + h * TAB_PER_H + dyi * TAB_ROW + 63)
                                  : nullptr;
    float scale = 0.f;
    if (!USE_TAB) {
        float w  = weight[h];
        float lw = w > 0.f ? w : 0.01f * w;
        scale = -lw * 1.44269504088896f;
    }

#pragma unroll
    for (int half = 0; half < 2; ++half) {
        if (half) __syncthreads();   // drain of previous half must finish
        // ---- apply decay + write to LDS (swizzled) ----
#pragma unroll
        for (int ii = 0; ii < 2; ++ii) {
            const int i  = half * 2 + ii;
            const int qx = i * 16 + r16;              // global row & 63
            const int lrow = wr * 32 + ii * 16 + r16; // LDS row 0..63
#pragma unroll
            for (int j = 0; j < 4; ++j) {
                f32x4 t;
                if (USE_TAB) {
                    const float* rp = tabrow - qx + kg * 4 + j * 16;
                    t[0] = rp[0]; t[1] = rp[1]; t[2] = rp[2]; t[3] = rp[3];
                } else {
                    float qy = (float)((row0 + qx) >> 6);
#pragma unroll
                    for (int r = 0; r < 4; ++r) {
                        int col = col0 + j * 16 + kg * 4 + r;
                        float kx = (float)(col & (EXQ - 1));
                        float ky = (float)(col >> 6);
                        float dx = kx - (float)qx, dy = ky - qy;
                        t[r] = exp2f(scale * sqrtf(dx * dx + dy * dy));
                    }
                }
                int col16 = wc * 16 + j * 4 + kg;          // 16-B slot 0..31
                int slot  = col16 ^ (lrow & 7);            // swizzle
                *reinterpret_cast<f32x4*>(&lds[lrow * 128 + slot * 4]) =
                    acc[i][j] * t;
            }
        }
        __syncthreads();
        // ---- drain: 8 instrs/wave, each 2 rows x 512 B contiguous ----
        const int c32 = lane & 31;                     // linear 16-B slot
#pragma unroll
        for (int tI = 0; tI < 8; ++tI) {
            int lr = wave * 16 + tI * 2 + (lane >> 5); // LDS row 0..63
            int slot = c32 ^ (lr & 7);
            f32x4 v = *reinterpret_cast<const f32x4*>(&lds[lr * 128 + slot * 4]);
            int wr_ = lr >> 5;
            int i   = half * 2 + ((lr >> 4) & 1);
            int grow = brow0 + wr_ * 64 + i * 16 + (lr & 15);
            float* op = out + ((size_t)bh * SEQ + grow) * SEQ + bcol0 + c32 * 4;
            __builtin_nontemporal_store(v, reinterpret_cast<f32x4*>(op));
        }
    }
}

extern "C" void kernel_launch(void* const* d_in, const int* in_sizes, int n_in,
                              void* d_out, int out_size, void* d_ws, size_t ws_size,
                              hipStream_t stream) {
    const float* q  = (const float*)d_in[0];
    const float* b  = (const float*)d_in[1];
    const float* fr = (const float*)d_in[2];
    const float* wt = (const float*)d_in[3];
    float* out = (float*)d_out;

    const size_t need_tensors = 2 * TENSOR_ELEMS * sizeof(unsigned short);
    const size_t need_full    = need_tensors + TAB_ELEMS * sizeof(float);
    if (ws_size < need_tensors) return;
    const bool use_tab = ws_size >= need_full;

    unsigned short* ws16 = (unsigned short*)d_ws;
    float* tab = (float*)(ws16 + 2 * TENSOR_ELEMS);

    int grid1 = ROPE_BLOCKS + (use_tab ? TAB_BLOCKS : 0);
    phase1_kernel<<<grid1, 256, 0, stream>>>(q, b, fr, wt,
                                             (unsigned int*)d_ws, tab,
                                             use_tab ? 1 : 0);

    dim3 grid(SEQ / 128, SEQ / 128, BQ * NH);
    if (use_tab)
        gemm_delta_kernel<true><<<grid, 256, 0, stream>>>(ws16, tab, wt, out);
    else
        gemm_delta_kernel<false><<<grid, 256, 0, stream>>>(ws16, tab, wt, out);
}